// Round 1
// 475.627 us; speedup vs baseline: 1.4807x; 1.4807x over previous
//
#include <hip/hip_runtime.h>
#include <math.h>
#include <stdint.h>

#define NB      65536
#define LIN     274
#define SEQ     18
#define DM      16
#define NH      4
#define HID     64
#define NLAYER  4
#define EPSF    1e-5f

// ---- MFMA-path config ----
#define EPB      8                 // batch elements per block
#define NTHREADS 192               // 3 waves; 144 tokens = 9 row-tiles of 16, 3 tiles/wave
// LDS: K as f16x4 per (elem,h,s): 8*4*18*8B = 4608B ; V as f32x4: 9216B ; total 13824B
#define SMEM_F32 3456
#define VOFF_F32 1152

typedef _Float16 h2    __attribute__((ext_vector_type(2)));
typedef _Float16 f16x4 __attribute__((ext_vector_type(4)));
typedef float    f32x4 __attribute__((ext_vector_type(4)));
typedef __fp16   hf2_raw __attribute__((ext_vector_type(2)));

#if __has_builtin(__builtin_amdgcn_fdot2)
__device__ __forceinline__ float fdot2(h2 a, h2 b, float c) { return __builtin_amdgcn_fdot2(a, b, c, false); }
#else
__device__ __forceinline__ float fdot2(h2 a, h2 b, float c) { return c + (float)a[0] * (float)b[0] + (float)a[1] * (float)b[1]; }
#endif
#if __has_builtin(__builtin_amdgcn_cvt_pkrtz)
__device__ __forceinline__ h2 pkrtz(float a, float b) {
    hf2_raw r = __builtin_amdgcn_cvt_pkrtz(a, b);
    return __builtin_bit_cast(h2, r);
}
#else
__device__ __forceinline__ h2 pkrtz(float a, float b) { h2 r; r[0] = (_Float16)a; r[1] = (_Float16)b; return r; }
#endif

#if __has_builtin(__builtin_amdgcn_mfma_f32_16x16x16f16)
__device__ __forceinline__ f32x4 MFMA16(f16x4 a, f16x4 b, f32x4 c) {
    return __builtin_amdgcn_mfma_f32_16x16x16f16(a, b, c, 0, 0, 0);
}
#elif __has_builtin(__builtin_amdgcn_mfma_f32_16x16x16_f16)
__device__ __forceinline__ f32x4 MFMA16(f16x4 a, f16x4 b, f32x4 c) {
    return __builtin_amdgcn_mfma_f32_16x16x16_f16(a, b, c, 0, 0, 0);
}
#else
__device__ __forceinline__ f32x4 MFMA16(f16x4 a, f16x4 b, f32x4 c) {
    f32x4 d;
    asm volatile("v_mfma_f32_16x16x16_f16 %0, %1, %2, %3"
                 : "=v"(d) : "v"(a), "v"(b), "v"(c));
    return d;
}
#endif

__device__ __forceinline__ float fast_rcp(float x)  { return __builtin_amdgcn_rcpf(x); }
__device__ __forceinline__ float fast_rsq(float x)  { return __builtin_amdgcn_rsqf(x); }
__device__ __forceinline__ float fast_exp2(float x) { return __builtin_amdgcn_exp2f(x); }

__device__ __forceinline__ float gelu_tanh(float t) {
    const float A = 0.79788456080286536f;           // sqrt(2/pi)
    const float B = 0.03567740814183430f;           // A*0.044715
    float t2 = t * t;
    float u  = t * fmaf(t2, B, A);
    float e  = fast_exp2(u * 2.88539008177792681f); // e^{2u}
    float r  = fast_rcp(e + 1.0f);
    return fmaf(-t, r, t);
}

__device__ __forceinline__ f16x4 pk4(float a, float b, float c, float d) {
    h2 lo = pkrtz(a, b), hi = pkrtz(c, d);
    f16x4 r; r[0] = lo[0]; r[1] = lo[1]; r[2] = hi[0]; r[3] = hi[1];
    return r;
}
__device__ __forceinline__ f32x4 ld4(const float* p) {
    float4 t = *(const float4*)p;
    f32x4 r; r[0] = t.x; r[1] = t.y; r[2] = t.z; r[3] = t.w;
    return r;
}

// ---- weight fragments in d_ws ----
// 50 tiles of 64 lanes x 4 f16 (A-fragment: lane holds A[row=l&15][k=(l>>4)*4+i]).
// tile 0: patchify W[d][k]     tile 1: decoder A[m=kpos][kk=d] = dec_w[d][kpos]
// per layer li (base 2+li*12): j=0..2 qkv rows j*16.. ; j=3 out_w ; j=4..7 w1 chunks ; j=8..11 w2 k-chunks
#define WS_H2_COUNT 6400   // 50 tiles * 64 lanes * 2 h2 = 25600 B

__global__ __launch_bounds__(512) void prep_weights(
    const float* __restrict__ patch_w, const float* __restrict__ dec_w,
    const float* __restrict__ qkv_w, const float* __restrict__ out_w,
    const float* __restrict__ mlp_w1, const float* __restrict__ mlp_w2,
    h2* __restrict__ ws)
{
    int i = blockIdx.x * 512 + threadIdx.x;
    if (i >= WS_H2_COUNT) return;
    int tile = i >> 7;
    int lane = (i >> 1) & 63;
    int p    = i & 1;
    int row  = lane & 15;
    int kb   = (lane >> 4) * 4 + 2 * p;
    float a, b;
    if (tile == 0)      { a = patch_w[row * 16 + kb];     b = patch_w[row * 16 + kb + 1]; }
    else if (tile == 1) { a = dec_w[kb * 16 + row];       b = dec_w[(kb + 1) * 16 + row]; }
    else {
        int t2 = tile - 2, li = t2 / 12, j = t2 % 12;
        const float* s;
        if (j < 3)       s = qkv_w  + li * 768  + (j * 16 + row) * 16 + kb;
        else if (j == 3) s = out_w  + li * 256  + row * 16 + kb;
        else if (j < 8)  s = mlp_w1 + li * 1024 + ((j - 4) * 16 + row) * 16 + kb;
        else             s = mlp_w2 + li * 1024 + row * 64 + (j - 8) * 16 + kb;
        a = s[0]; b = s[1];
    }
    ws[i] = pkrtz(a, b);
}

__global__ __launch_bounds__(NTHREADS) void ae_fwd(
    const float* __restrict__ x,
    const float* __restrict__ patch_b, const float* __restrict__ pos_embed,
    const float* __restrict__ ln1_g, const float* __restrict__ ln1_b,
    const h2*    __restrict__ wp,
    const float* __restrict__ qkv_b, const float* __restrict__ out_b,
    const float* __restrict__ ln2_g, const float* __restrict__ ln2_b,
    const float* __restrict__ mlp_b1, const float* __restrict__ mlp_b2,
    const float* __restrict__ lnf_g, const float* __restrict__ lnf_b,
    const float* __restrict__ dec_b,
    float* __restrict__ out_y, float* __restrict__ out_z)
{
    __shared__ float smem[SMEM_F32];
    const int tid  = threadIdx.x;
    const int lane = tid & 63;
    const int wv   = tid >> 6;       // 0..2
    const int col  = lane & 15;      // token-within-tile (MFMA col)
    const int g16  = lane >> 4;      // 0..3: k-group AND head index
    const int fb   = g16 * 4;        // this lane's feature base

    // ---- stage x (coalesced float4) ----
    {
        const float4* xg = (const float4*)(x + (long long)blockIdx.x * (EPB * LIN));
        float4* xs = (float4*)smem;
        for (int i = tid; i < (EPB * LIN) / 4; i += NTHREADS) xs[i] = xg[i];
    }
    __syncthreads();

    // ---- per-tile token -> (element, seq) ----
    int elemL[3], sIdx[3];
    #pragma unroll
    for (int t = 0; t < 3; ++t) {
        int T = wv * 48 + t * 16 + col;      // 0..143
        int e = (T * 57) >> 10;              // floor(T/18), exact for T<504
        elemL[t] = e;
        sIdx[t]  = T - 18 * e;
    }

    const f16x4* wfrag = (const f16x4*)wp;
    const f16x4 wpatch = wfrag[lane];
    const f16x4 wdec   = wfrag[64 + lane];

    // ---- patchify via MFMA (h stays in activation fragment layout) ----
    float hacc[3][4];
    {
        const float4 pb = *(const float4*)(patch_b + fb);
        #pragma unroll
        for (int t = 0; t < 3; ++t) {
            float xv[4];
            #pragma unroll
            for (int r = 0; r < 4; ++r) {
                int loc = sIdx[t] * 16 - 7 + fb + r;
                xv[r] = (loc >= 0 && loc < LIN) ? smem[elemL[t] * LIN + loc] : 0.0f;
            }
            f16x4 xb = pk4(xv[0], xv[1], xv[2], xv[3]);
            const float4 pe = *(const float4*)(pos_embed + sIdx[t] * DM + fb);
            f32x4 c; c[0] = pb.x + pe.x; c[1] = pb.y + pe.y; c[2] = pb.z + pe.z; c[3] = pb.w + pe.w;
            c = MFMA16(wpatch, xb, c);
            #pragma unroll
            for (int r = 0; r < 4; ++r) hacc[t][r] = c[r];
        }
    }

    h2*    Kl = (h2*)smem;            // f16x4 idx: elem*72 + h*18 + s
    float* Vl = smem + VOFF_F32;      // f32  idx: elem*288 + (h*18+s)*4

    #pragma unroll 1
    for (int li = 0; li < NLAYER; ++li) {
        const f16x4* wl = wfrag + (2 + li * 12) * 64 + lane;

        // ---- LN1 + QKV (register-only; publish after barrier) ----
        const float4 g1 = *(const float4*)(ln1_g + li * DM + fb);
        const float4 b1 = *(const float4*)(ln1_b + li * DM + fb);
        h2 qp[3][2]; f16x4 kpk[3]; f32x4 vreg[3];
        #pragma unroll
        for (int t = 0; t < 3; ++t) {
            float a0 = hacc[t][0], a1 = hacc[t][1], a2 = hacc[t][2], a3 = hacc[t][3];
            float sm = a0 + a1 + a2 + a3;
            sm += __shfl_xor(sm, 16); sm += __shfl_xor(sm, 32);
            float mean = sm * (1.0f / 16.0f);
            float d0 = a0 - mean, d1 = a1 - mean, d2 = a2 - mean, d3 = a3 - mean;
            float vs = d0 * d0 + d1 * d1 + d2 * d2 + d3 * d3;
            vs += __shfl_xor(vs, 16); vs += __shfl_xor(vs, 32);
            float inv = fast_rsq(vs * (1.0f / 16.0f) + EPSF);
            f16x4 xb = pk4(d0 * inv * g1.x + b1.x, d1 * inv * g1.y + b1.y,
                           d2 * inv * g1.z + b1.z, d3 * inv * g1.w + b1.w);
            f32x4 aq = ld4(qkv_b + li * 48 + fb);
            f32x4 ak = ld4(qkv_b + li * 48 + 16 + fb);
            f32x4 av = ld4(qkv_b + li * 48 + 32 + fb);
            aq = MFMA16(wl[0],   xb, aq);
            ak = MFMA16(wl[64],  xb, ak);
            av = MFMA16(wl[128], xb, av);
            const float qs = 0.72134752044448170f;  // (1/sqrt(4)) * log2(e)
            qp[t][0] = pkrtz(aq[0] * qs, aq[1] * qs);
            qp[t][1] = pkrtz(aq[2] * qs, aq[3] * qs);
            kpk[t] = pk4(ak[0], ak[1], ak[2], ak[3]);
            vreg[t] = av;
        }
        __syncthreads();   // previous-layer K/V readers done
        #pragma unroll
        for (int t = 0; t < 3; ++t) {
            ((f16x4*)Kl)[elemL[t] * 72 + g16 * 18 + sIdx[t]] = kpk[t];
            float4 vv; vv.x = vreg[t][0]; vv.y = vreg[t][1]; vv.z = vreg[t][2]; vv.w = vreg[t][3];
            *(float4*)(Vl + elemL[t] * 288 + (g16 * 18 + sIdx[t]) * 4) = vv;
        }
        __syncthreads();   // K/V visible

        // ---- attention (lane = (head g16, token col): softmax fully lane-local) + out-proj ----
        const float4 ob4 = *(const float4*)(out_b + li * DM + fb);
        #pragma unroll
        for (int t = 0; t < 3; ++t) {
            const f16x4* kb = (const f16x4*)Kl + elemL[t] * 72 + g16 * 18;
            float sc[SEQ]; float ssum = 0.0f;
            #pragma unroll
            for (int j = 0; j < SEQ; ++j) {
                f16x4 kj = kb[j];
                h2 k0; k0[0] = kj[0]; k0[1] = kj[1];
                h2 k1; k1[0] = kj[2]; k1[1] = kj[3];
                float sv = fdot2(qp[t][1], k1, fdot2(qp[t][0], k0, 0.0f));
                float w  = fast_exp2(sv);
                sc[j] = w; ssum += w;
            }
            float inv = fast_rcp(ssum);
            const float4* vb = (const float4*)(Vl + elemL[t] * 288 + g16 * 72);
            float o0 = 0.f, o1 = 0.f, o2 = 0.f, o3 = 0.f;
            #pragma unroll
            for (int j = 0; j < SEQ; ++j) {
                float4 vj = vb[j];
                float w = sc[j];
                o0 = fmaf(w, vj.x, o0); o1 = fmaf(w, vj.y, o1);
                o2 = fmaf(w, vj.z, o2); o3 = fmaf(w, vj.w, o3);
            }
            f16x4 obf = pk4(o0 * inv, o1 * inv, o2 * inv, o3 * inv);
            f32x4 oa; oa[0] = ob4.x; oa[1] = ob4.y; oa[2] = ob4.z; oa[3] = ob4.w;
            oa = MFMA16(wl[3 * 64], obf, oa);
            #pragma unroll
            for (int r = 0; r < 4; ++r) hacc[t][r] += oa[r];
        }

        // ---- LN2 + MLP (all lane-local chaining) ----
        const float4 g2 = *(const float4*)(ln2_g + li * DM + fb);
        const float4 b2 = *(const float4*)(ln2_b + li * DM + fb);
        #pragma unroll
        for (int t = 0; t < 3; ++t) {
            float a0 = hacc[t][0], a1 = hacc[t][1], a2 = hacc[t][2], a3 = hacc[t][3];
            float sm = a0 + a1 + a2 + a3;
            sm += __shfl_xor(sm, 16); sm += __shfl_xor(sm, 32);
            float mean = sm * (1.0f / 16.0f);
            float d0 = a0 - mean, d1 = a1 - mean, d2 = a2 - mean, d3 = a3 - mean;
            float vs = d0 * d0 + d1 * d1 + d2 * d2 + d3 * d3;
            vs += __shfl_xor(vs, 16); vs += __shfl_xor(vs, 32);
            float inv = fast_rsq(vs * (1.0f / 16.0f) + EPSF);
            f16x4 xb2 = pk4(d0 * inv * g2.x + b2.x, d1 * inv * g2.y + b2.y,
                            d2 * inv * g2.z + b2.z, d3 * inv * g2.w + b2.w);
            f32x4 acc2 = ld4(mlp_b2 + li * DM + fb);
            #pragma unroll
            for (int c = 0; c < 4; ++c) {
                f32x4 m1 = ld4(mlp_b1 + li * HID + c * 16 + fb);
                m1 = MFMA16(wl[(4 + c) * 64], xb2, m1);
                f16x4 gb = pk4(gelu_tanh(m1[0]), gelu_tanh(m1[1]),
                               gelu_tanh(m1[2]), gelu_tanh(m1[3]));
                acc2 = MFMA16(wl[(8 + c) * 64], gb, acc2);
            }
            #pragma unroll
            for (int r = 0; r < 4; ++r) hacc[t][r] += acc2[r];
        }
    }

    // ---- final LN + z + decoder (MFMA) + y ----
    const float4 gf = *(const float4*)(lnf_g + fb);
    const float4 bf = *(const float4*)(lnf_b + fb);
    const float db0 = dec_b[0];
    #pragma unroll
    for (int t = 0; t < 3; ++t) {
        float a0 = hacc[t][0], a1 = hacc[t][1], a2 = hacc[t][2], a3 = hacc[t][3];
        float sm = a0 + a1 + a2 + a3;
        sm += __shfl_xor(sm, 16); sm += __shfl_xor(sm, 32);
        float mean = sm * (1.0f / 16.0f);
        float d0 = a0 - mean, d1 = a1 - mean, d2 = a2 - mean, d3 = a3 - mean;
        float vs = d0 * d0 + d1 * d1 + d2 * d2 + d3 * d3;
        vs += __shfl_xor(vs, 16); vs += __shfl_xor(vs, 32);
        float inv = fast_rsq(vs * (1.0f / 16.0f) + EPSF);
        float f0 = d0 * inv * gf.x + bf.x;
        float f1 = d1 * inv * gf.y + bf.y;
        float f2 = d2 * inv * gf.z + bf.z;
        float f3 = d3 * inv * gf.w + bf.w;

        long long eg = (long long)blockIdx.x * EPB + elemL[t];
        float* zb = out_z + eg * (DM * SEQ) + sIdx[t];
        zb[(fb + 0) * SEQ] = f0; zb[(fb + 1) * SEQ] = f1;
        zb[(fb + 2) * SEQ] = f2; zb[(fb + 3) * SEQ] = f3;

        f16x4 hb = pk4(f0, f1, f2, f3);
        f32x4 y4 = {0.f, 0.f, 0.f, 0.f};
        y4 = MFMA16(wdec, hb, y4);
        float* yb = out_y + eg * LIN;
        int p0 = sIdx[t] * 16 + fb - 7;
        #pragma unroll
        for (int r = 0; r < 4; ++r) {
            int p = p0 + r;
            if (p >= 0 && p < LIN) yb[p] = y4[r] + db0;
        }
    }
}

// ---------------- fp32 fallback (used only if ws_size is too small) ----------------
#define EPB_F 14
#define NT_F  252
__global__ __launch_bounds__(NT_F) void ae_fwd_f32(
    const float* __restrict__ x,
    const float* __restrict__ patch_w, const float* __restrict__ patch_b,
    const float* __restrict__ pos_embed,
    const float* __restrict__ ln1_g, const float* __restrict__ ln1_b,
    const float* __restrict__ qkv_w, const float* __restrict__ qkv_b,
    const float* __restrict__ out_w, const float* __restrict__ out_b,
    const float* __restrict__ ln2_g, const float* __restrict__ ln2_b,
    const float* __restrict__ mlp_w1, const float* __restrict__ mlp_b1,
    const float* __restrict__ mlp_w2, const float* __restrict__ mlp_b2,
    const float* __restrict__ lnf_g, const float* __restrict__ lnf_b,
    const float* __restrict__ dec_w, const float* __restrict__ dec_b,
    float* __restrict__ out_y, float* __restrict__ out_z)
{
    __shared__ float s_kv[EPB_F * 580];
    const int tid = threadIdx.x;
    const int e   = tid / SEQ;
    const int s   = tid - e * SEQ;
    const long long b = (long long)blockIdx.x * EPB_F + e;
    const bool valid = (b < NB);
    {
        const long long base = (long long)blockIdx.x * (EPB_F * LIN);
        const long long lim  = (long long)NB * LIN - 1;
        for (int i = tid; i < EPB_F * LIN; i += NT_F) {
            long long gi = base + i;
            if (gi > lim) gi = lim;
            s_kv[i] = x[gi];
        }
    }
    __syncthreads();
    float xv[16];
    {
        const float* xe = &s_kv[e * LIN];
        #pragma unroll
        for (int k = 0; k < 16; ++k) {
            int idx = s * 16 - 7 + k;
            xv[k] = (idx >= 0 && idx < LIN) ? xe[idx] : 0.0f;
        }
    }
    float h[DM];
    #pragma unroll
    for (int d = 0; d < DM; ++d) {
        float acc = patch_b[d] + pos_embed[s * DM + d];
        #pragma unroll
        for (int k = 0; k < 16; ++k) acc = fmaf(xv[k], patch_w[d * 16 + k], acc);
        h[d] = acc;
    }
    #pragma unroll 1
    for (int li = 0; li < NLAYER; ++li) {
        float xn[DM];
        {
            float m = 0.f;
            #pragma unroll
            for (int d = 0; d < DM; ++d) m += h[d];
            m *= (1.0f / DM);
            float v = 0.f;
            #pragma unroll
            for (int d = 0; d < DM; ++d) { float t = h[d] - m; v = fmaf(t, t, v); }
            v *= (1.0f / DM);
            float inv = fast_rsq(v + EPSF);
            #pragma unroll
            for (int d = 0; d < DM; ++d) xn[d] = (h[d] - m) * inv * ln1_g[li * DM + d] + ln1_b[li * DM + d];
        }
        float q[DM], kk[DM], vv[DM];
        {
            const float* W  = qkv_w + li * 48 * DM;
            const float* Wb = qkv_b + li * 48;
            #pragma unroll
            for (int j = 0; j < DM; ++j) {
                float aq = Wb[j], ak = Wb[DM + j], av = Wb[2 * DM + j];
                #pragma unroll
                for (int d = 0; d < DM; ++d) {
                    float xd = xn[d];
                    aq = fmaf(xd, W[j * DM + d], aq);
                    ak = fmaf(xd, W[(DM + j) * DM + d], ak);
                    av = fmaf(xd, W[(2 * DM + j) * DM + d], av);
                }
                q[j] = aq; kk[j] = ak; vv[j] = av;
            }
        }
        __syncthreads();
        {
            float* kb = &s_kv[e * 580];
            float* vb = kb + SEQ * DM;
            #pragma unroll
            for (int j = 0; j < DM; ++j) kb[s * DM + j] = kk[j];
            #pragma unroll
            for (int j = 0; j < DM; ++j) vb[s * DM + j] = vv[j];
        }
        __syncthreads();
        float o[DM];
        {
            const float* kb = &s_kv[e * 580];
            const float* vb = kb + SEQ * DM;
            #pragma unroll
            for (int hh = 0; hh < NH; ++hh) {
                const float qscale = 0.5f * 1.44269504088896341f;
                const float q0 = q[hh * 4] * qscale, q1 = q[hh * 4 + 1] * qscale;
                const float q2 = q[hh * 4 + 2] * qscale, q3 = q[hh * 4 + 3] * qscale;
                float sc[SEQ];
                float ssum = 0.f;
                #pragma unroll
                for (int j = 0; j < SEQ; ++j) {
                    const float4 kj = *(const float4*)(kb + j * DM + hh * 4);
                    float t = fmaf(q0, kj.x, fmaf(q1, kj.y, fmaf(q2, kj.z, q3 * kj.w)));
                    float w = fast_exp2(t);
                    sc[j] = w; ssum += w;
                }
                const float inv = fast_rcp(ssum);
                float a0 = 0.f, a1 = 0.f, a2 = 0.f, a3 = 0.f;
                #pragma unroll
                for (int j = 0; j < SEQ; ++j) {
                    const float4 vj = *(const float4*)(vb + j * DM + hh * 4);
                    const float w = sc[j] * inv;
                    a0 = fmaf(w, vj.x, a0); a1 = fmaf(w, vj.y, a1);
                    a2 = fmaf(w, vj.z, a2); a3 = fmaf(w, vj.w, a3);
                }
                o[hh * 4] = a0; o[hh * 4 + 1] = a1; o[hh * 4 + 2] = a2; o[hh * 4 + 3] = a3;
            }
        }
        {
            const float* W  = out_w + li * DM * DM;
            #pragma unroll
            for (int d = 0; d < DM; ++d) {
                float acc = out_b[li * DM + d];
                #pragma unroll
                for (int d2 = 0; d2 < DM; ++d2) acc = fmaf(o[d2], W[d * DM + d2], acc);
                h[d] += acc;
            }
        }
        float xn2[DM];
        {
            float m = 0.f;
            #pragma unroll
            for (int d = 0; d < DM; ++d) m += h[d];
            m *= (1.0f / DM);
            float v = 0.f;
            #pragma unroll
            for (int d = 0; d < DM; ++d) { float t = h[d] - m; v = fmaf(t, t, v); }
            v *= (1.0f / DM);
            float inv = fast_rsq(v + EPSF);
            #pragma unroll
            for (int d = 0; d < DM; ++d) xn2[d] = (h[d] - m) * inv * ln2_g[li * DM + d] + ln2_b[li * DM + d];
        }
        {
            const float* W1 = mlp_w1 + li * HID * DM;
            const float* W2 = mlp_w2 + li * DM * HID;
            float acc2[DM];
            #pragma unroll
            for (int d = 0; d < DM; ++d) acc2[d] = mlp_b2[li * DM + d];
            #pragma unroll 2
            for (int j = 0; j < HID; ++j) {
                float t = mlp_b1[li * HID + j];
                #pragma unroll
                for (int d = 0; d < DM; ++d) t = fmaf(xn2[d], W1[j * DM + d], t);
                float g = gelu_tanh(t);
                #pragma unroll
                for (int d = 0; d < DM; ++d) acc2[d] = fmaf(g, W2[d * HID + j], acc2[d]);
            }
            #pragma unroll
            for (int d = 0; d < DM; ++d) h[d] += acc2[d];
        }
    }
    {
        float m = 0.f;
        #pragma unroll
        for (int d = 0; d < DM; ++d) m += h[d];
        m *= (1.0f / DM);
        float v = 0.f;
        #pragma unroll
        for (int d = 0; d < DM; ++d) { float t = h[d] - m; v = fmaf(t, t, v); }
        v *= (1.0f / DM);
        float inv = fast_rsq(v + EPSF);
        #pragma unroll
        for (int d = 0; d < DM; ++d) h[d] = (h[d] - m) * inv * lnf_g[d] + lnf_b[d];
    }
    if (valid) {
        float* zb = out_z + b * (DM * SEQ);
        #pragma unroll
        for (int d = 0; d < DM; ++d) zb[d * SEQ + s] = h[d];
        float* yb = out_y + b * LIN;
        const float db0 = dec_b[0];
        #pragma unroll
        for (int k = 0; k < 16; ++k) {
            int t = s * 16 + k - 7;
            if (t >= 0 && t < LIN) {
                float acc = db0;
                #pragma unroll
                for (int d = 0; d < DM; ++d) acc = fmaf(h[d], dec_w[d * 16 + k], acc);
                yb[t] = acc;
            }
        }
    }
}

extern "C" void kernel_launch(void* const* d_in, const int* in_sizes, int n_in,
                              void* d_out, int out_size, void* d_ws, size_t ws_size,
                              hipStream_t stream) {
    const float* x        = (const float*)d_in[0];
    const float* patch_w  = (const float*)d_in[1];
    const float* patch_b  = (const float*)d_in[2];
    const float* pos_e    = (const float*)d_in[3];
    const float* ln1_g    = (const float*)d_in[4];
    const float* ln1_b    = (const float*)d_in[5];
    const float* qkv_w    = (const float*)d_in[6];
    const float* qkv_b    = (const float*)d_in[7];
    const float* out_w    = (const float*)d_in[8];
    const float* out_b    = (const float*)d_in[9];
    const float* ln2_g    = (const float*)d_in[10];
    const float* ln2_b    = (const float*)d_in[11];
    const float* mlp_w1   = (const float*)d_in[12];
    const float* mlp_b1   = (const float*)d_in[13];
    const float* mlp_w2   = (const float*)d_in[14];
    const float* mlp_b2   = (const float*)d_in[15];
    const float* lnf_g    = (const float*)d_in[16];
    const float* lnf_b    = (const float*)d_in[17];
    const float* dec_w    = (const float*)d_in[18];
    const float* dec_b    = (const float*)d_in[19];

    float* out_y = (float*)d_out;                       // (B,1,274) first
    float* out_z = out_y + (long long)NB * LIN;         // then (B,16,18)

    if (ws_size >= WS_H2_COUNT * sizeof(h2)) {
        h2* wsp = (h2*)d_ws;
        prep_weights<<<(WS_H2_COUNT + 511) / 512, 512, 0, stream>>>(
            patch_w, dec_w, qkv_w, out_w, mlp_w1, mlp_w2, wsp);
        ae_fwd<<<NB / EPB, NTHREADS, 0, stream>>>(
            x, patch_b, pos_e, ln1_g, ln1_b, wsp,
            qkv_b, out_b, ln2_g, ln2_b, mlp_b1, mlp_b2,
            lnf_g, lnf_b, dec_b, out_y, out_z);
    } else {
        const int grid = (NB + EPB_F - 1) / EPB_F;
        ae_fwd_f32<<<grid, NT_F, 0, stream>>>(
            x, patch_w, patch_b, pos_e, ln1_g, ln1_b, qkv_w, qkv_b,
            out_w, out_b, ln2_g, ln2_b, mlp_w1, mlp_b1, mlp_w2, mlp_b2,
            lnf_g, lnf_b, dec_w, dec_b, out_y, out_z);
    }
}